// Round 13
// baseline (2931.868 us; speedup 1.0000x reference)
//
#include <hip/hip_runtime.h>
#include <stdint.h>

// Forbid mul+add contraction: pk_fma would change rounding vs the reference's
// separate mul/add ops. Critical scalar math also uses explicit __f*_rn.
#pragma clang fp contract(off)

typedef unsigned long long u64;
typedef unsigned int u32;
typedef float v2f __attribute__((ext_vector_type(2)));

#define BB 8
#define NN 4096
#define SS 1024
#define EE 102      // int(0.1 * 1024)
#define NBB 3072    // N - S
#define FT 256      // fps threads (4 waves, 1 per SIMD)
#define PT 16       // points per thread (contiguous: thread t owns [16t,16t+16))
#define SEL_T 512

// DPP wave64 max-reduce step (bound_ctrl: OOB lanes read 0; values >= 0).
template <int CTRL>
__device__ __forceinline__ float maxdpp(float v) {
  int m = __builtin_amdgcn_update_dpp(0, __float_as_int(v), CTRL, 0xf, 0xf, true);
  return fmaxf(v, __int_as_float(m));
}

// ---------------- FPS kernel: one block per batch ----------------
// Exact replica of _fps_order: d = (dx*dx+dy*dy)+dz*dz (no FMA), mind=min,
// argmax with lowest-index-first ties. r12 base (scalar register arrays +
// 64KB AoS mirror = broadcast source AND PromoteAlloca demotion shield;
// hist[] in LDS; winner lane publishes its own key). ONE change vs r12:
// the 16-deep serial select chain is replaced by a log-depth exact fmax
// tree (serial ~20 cyc instead of ~128) + an equality bitmask + ctz for
// the lowest tied slot, whose independent compares issue inside the DPP
// chain's dependency stalls. Tie rules preserved at all three levels.
__global__ __launch_bounds__(FT) void fps_kernel(const float* __restrict__ x,
                                                 int* __restrict__ idxs) {
  const int b = blockIdx.x;
  const int t = threadIdx.x;
  const int w = t >> 6;
  const int lane = t & 63;
  const float* xb = x + (size_t)b * NN * 3;

  __shared__ float4 lxyz[NN];   // 64 KB coord mirror (+ demotion shield)
  __shared__ int hist[NN];      // 16 KB FPS order (LDS-local until flush)
  __shared__ u64 rkey[2][4];    // per-wave candidate keys, double-buffered

  float px[PT], py[PT], pz[PT], mind[PT];

  // load 16 contiguous points = 12 float4 per thread (fully coalesced block)
  const float4* xb4 = (const float4*)xb;
  float4 f[12];
#pragma unroll
  for (int j = 0; j < 12; ++j) f[j] = xb4[t * 12 + j];
#pragma unroll
  for (int g = 0; g < 4; ++g) {
    float4 a = f[g * 3 + 0], c = f[g * 3 + 1], d = f[g * 3 + 2];
    px[g * 4 + 0] = a.x; py[g * 4 + 0] = a.y; pz[g * 4 + 0] = a.z;
    px[g * 4 + 1] = a.w; py[g * 4 + 1] = c.x; pz[g * 4 + 1] = c.y;
    px[g * 4 + 2] = c.z; py[g * 4 + 2] = c.w; pz[g * 4 + 2] = d.x;
    px[g * 4 + 3] = d.y; py[g * 4 + 3] = d.z; pz[g * 4 + 3] = d.w;
  }
#pragma unroll
  for (int q = 0; q < PT; ++q) {
    lxyz[t * PT + q] = make_float4(px[q], py[q], pz[q], 0.0f);
    mind[q] = __builtin_inff();
  }
  if (t == 0) hist[0] = 0;
  __syncthreads();

  float4 lp = lxyz[0];
  for (int it = 0; it < NN - 1; ++it) {
    const int buf = it & 1;
    v2f lx2; lx2.x = lp.x; lx2.y = lp.x;
    v2f ly2; ly2.x = lp.y; ly2.y = lp.y;
    v2f lz2; lz2.x = lp.z; lz2.y = lp.z;

    // phase 1: packed-f32 distances + mind update only (no serial select;
    // per-half rn rounding == scalar rn)
#pragma unroll
    for (int q = 0; q < 8; ++q) {
      v2f X; X.x = px[2 * q]; X.y = px[2 * q + 1];
      v2f Y; Y.x = py[2 * q]; Y.y = py[2 * q + 1];
      v2f Z; Z.x = pz[2 * q]; Z.y = pz[2 * q + 1];
      v2f dx = X - lx2;
      v2f dy = Y - ly2;
      v2f dz = Z - lz2;
      v2f dd = (dx * dx + dy * dy) + dz * dz;
      mind[2 * q] = fminf(mind[2 * q], dd.x);
      mind[2 * q + 1] = fminf(mind[2 * q + 1], dd.y);
    }

    // phase 1b: exact thread-local max, log depth (fmax exact for finites ->
    // same value the reference's serial scan produces)
    float a0 = fmaxf(mind[0], mind[1]),   a1 = fmaxf(mind[2], mind[3]);
    float a2 = fmaxf(mind[4], mind[5]),   a3 = fmaxf(mind[6], mind[7]);
    float a4 = fmaxf(mind[8], mind[9]),   a5 = fmaxf(mind[10], mind[11]);
    float a6 = fmaxf(mind[12], mind[13]), a7 = fmaxf(mind[14], mind[15]);
    float c0 = fmaxf(a0, a1), c1 = fmaxf(a2, a3);
    float c2 = fmaxf(a4, a5), c3 = fmaxf(a6, a7);
    float g0 = fmaxf(c0, c1), g1 = fmaxf(c2, c3);
    float bestv = fmaxf(g0, g1);

    // phase 2: wave64 max via DPP (all VALU): result in lane 63
    float r = bestv;
    r = maxdpp<0x111>(r);   // row_shr:1
    r = maxdpp<0x112>(r);   // row_shr:2
    r = maxdpp<0x114>(r);   // row_shr:4
    r = maxdpp<0x118>(r);   // row_shr:8
    r = maxdpp<0x142>(r);   // row_bcast:15
    r = maxdpp<0x143>(r);   // row_bcast:31

    // phase 2b (issues inside the DPP chain's dep stalls): lowest local slot
    // equal to the max -- reference tie rule: first index wins
    u32 qm = (mind[0] == bestv ? 0x0001u : 0u) | (mind[1] == bestv ? 0x0002u : 0u) |
             (mind[2] == bestv ? 0x0004u : 0u) | (mind[3] == bestv ? 0x0008u : 0u) |
             (mind[4] == bestv ? 0x0010u : 0u) | (mind[5] == bestv ? 0x0020u : 0u) |
             (mind[6] == bestv ? 0x0040u : 0u) | (mind[7] == bestv ? 0x0080u : 0u) |
             (mind[8] == bestv ? 0x0100u : 0u) | (mind[9] == bestv ? 0x0200u : 0u) |
             (mind[10] == bestv ? 0x0400u : 0u) | (mind[11] == bestv ? 0x0800u : 0u) |
             (mind[12] == bestv ? 0x1000u : 0u) | (mind[13] == bestv ? 0x2000u : 0u) |
             (mind[14] == bestv ? 0x4000u : 0u) | (mind[15] == bestv ? 0x8000u : 0u);
    int bq = (int)__builtin_ctz(qm);

    int wmaxb = __builtin_amdgcn_readlane(__float_as_int(r), 63);

    // phase 3: first lane holding the max == lowest candidate index; that
    // lane publishes the key itself (no second readlane)
    u64 msk = __ballot(__float_as_int(bestv) == wmaxb);
    int flane = (int)__builtin_ctzll(msk);
    if (lane == flane) {
      int besti = t * PT + bq;
      rkey[buf][w] = ((u64)(u32)wmaxb << 32) | (u32)(0xFFFFFFFFu - (u32)besti);
    }
    __syncthreads();

    // phase 4: 4-way key tree (value desc, index asc packed in u64);
    // slot reads are wave-uniform -> LDS broadcast
    u64 k0 = rkey[buf][0], k1 = rkey[buf][1];
    u64 k2 = rkey[buf][2], k3 = rkey[buf][3];
    u64 m01 = k0 > k1 ? k0 : k1;
    u64 m23 = k2 > k3 ? k2 : k3;
    u64 km = m01 > m23 ? m01 : m23;
    int last = (int)(0xFFFFFFFFu - (u32)(km & 0xFFFFFFFFu));
    if (t == 0) hist[it + 1] = last;   // LDS store: lgkm ack only, no vmcnt
    lp = lxyz[last];                   // broadcast read (same addr all lanes)
  }

  // flush FPS order to global once (coalesced int4: 4096/256/4 = 4 per thread)
  __syncthreads();
  int* ig = idxs + (size_t)b * NN;
#pragma unroll
  for (int j = 0; j < NN / FT / 4; ++j) {
    ((int4*)ig)[j * FT + t] = ((const int4*)hist)[j * FT + t];
  }
}

// ------------- selection kernel: one block per batch -------------
__global__ __launch_bounds__(SEL_T) void select_kernel(const float* __restrict__ x,
                                                       const float* __restrict__ curv,
                                                       const int* __restrict__ idxs,
                                                       float* __restrict__ out) {
  const int b = blockIdx.x;
  const int t = threadIdx.x;
  __shared__ u64 ka[SS];     // sca keys: (~vbits, i)  -> ascending == desc by v
  __shared__ u64 kb[4096];   // scb keys: (vbits, i)   -> ascending, 1024 pads
  __shared__ float rmn[8], rmx[8];

  const float* cb = curv + (size_t)b * NN;
  const int* ib = idxs + (size_t)b * NN;

  float mn = __builtin_inff(), mx = -__builtin_inff();
  float cv[8];
#pragma unroll
  for (int q = 0; q < 8; ++q) {
    float v = cb[q * SEL_T + t];
    cv[q] = v;
    mn = fminf(mn, v);
    mx = fmaxf(mx, v);
  }
#pragma unroll
  for (int s = 1; s < 64; s <<= 1) {
    mn = fminf(mn, __shfl_xor(mn, s, 64));
    mx = fmaxf(mx, __shfl_xor(mx, s, 64));
  }
  if ((t & 63) == 0) { rmn[t >> 6] = mn; rmx[t >> 6] = mx; }
  __syncthreads();
  mn = rmn[0]; mx = rmx[0];
#pragma unroll
  for (int w = 1; w < 8; ++w) { mn = fminf(mn, rmn[w]); mx = fmaxf(mx, rmx[w]); }
  float denom = __fsub_rn(mx, mn);

#pragma unroll
  for (int q = 0; q < 8; ++q) {
    int i = q * SEL_T + t;
    float cn = __fdiv_rn(__fsub_rn(cv[q], mn), denom);
    int id = ib[i];
    // jnp.linspace(1,0,4096)[id] = 1 - id/4095 (true division; id=4095 -> 0)
    float sv = __fsub_rn(1.0f, __fdiv_rn((float)id, 4095.0f));
    float scv = __fmul_rn(sv, cn);   // sc >= 0 -> bits are order-monotone
    u32 vb = __float_as_uint(scv);
    if (i < SS)
      ka[i] = ((u64)(vb ^ 0xFFFFFFFFu) << 32) | (u32)i;
    else
      kb[i - SS] = ((u64)vb << 32) | (u32)(i - SS);
  }
  for (int i = NBB + t; i < 4096; i += SEL_T) kb[i] = ~0ULL;  // pads to the top
  __syncthreads();

  // bitonic sort ka ascending (n=1024, 512 pairs: one per thread)
  for (u32 k = 2; k <= SS; k <<= 1) {
    for (u32 j = k >> 1; j > 0; j >>= 1) {
      u32 p = (u32)t;
      u32 i = ((p & ~(j - 1)) << 1) | (p & (j - 1));
      u32 l = i | j;
      bool up = ((i & k) == 0);
      u64 a = ka[i], c = ka[l];
      if ((a > c) == up) { ka[i] = c; ka[l] = a; }
      __syncthreads();
    }
  }
  // bitonic sort kb ascending (n=4096, 2048 pairs: 4 per thread)
  for (u32 k = 2; k <= 4096; k <<= 1) {
    for (u32 j = k >> 1; j > 0; j >>= 1) {
#pragma unroll
      for (u32 p = (u32)t; p < 2048; p += SEL_T) {
        u32 i = ((p & ~(j - 1)) << 1) | (p & (j - 1));
        u32 l = i | j;
        bool up = ((i & k) == 0);
        u64 a = kb[i], c = kb[l];
        if ((a > c) == up) { kb[i] = c; kb[l] = a; }
      }
      __syncthreads();
    }
  }

  // final[j]: j<922 -> ba_idx[j]; else tb beats ba ? tb_idx[j] : ba_idx[j]
#pragma unroll
  for (int j0 = 0; j0 < SS; j0 += SEL_T) {
    int j = j0 + t;
    u64 A = ka[j];
    int baid = (int)(u32)(A & 0xFFFFFFFFu);
    u32 babits = ((u32)(A >> 32)) ^ 0xFFFFFFFFu;
    int fin = baid;
    if (j >= SS - EE) {
      u64 Bk = kb[2048 + j];           // largest-1024 of scb, ascending
      u32 tbbits = (u32)(Bk >> 32);
      if (tbbits > babits) fin = (int)(u32)(Bk & 0xFFFFFFFFu) + SS;
    }
    int pt = ib[fin];
    out[(size_t)b * SS + j] = (float)fin;
    const float* xp = x + ((size_t)b * NN + (size_t)pt) * 3;
    float* op = out + (size_t)BB * SS + ((size_t)b * SS + (size_t)j) * 3;
    op[0] = xp[0];
    op[1] = xp[1];
    op[2] = xp[2];
  }
}

extern "C" void kernel_launch(void* const* d_in, const int* in_sizes, int n_in,
                              void* d_out, int out_size, void* d_ws, size_t ws_size,
                              hipStream_t stream) {
  (void)in_sizes; (void)n_in; (void)out_size; (void)ws_size;
  const float* x = (const float*)d_in[0];
  const float* curv = (const float*)d_in[1];
  int* idxs = (int*)d_ws;             // B*N int32 = 128 KB scratch
  float* out = (float*)d_out;

  fps_kernel<<<BB, FT, 0, stream>>>(x, idxs);
  select_kernel<<<BB, SEL_T, 0, stream>>>(x, curv, idxs, out);
}

// Round 14
// 2829.680 us; speedup vs baseline: 1.0361x; 1.0361x over previous
//
#include <hip/hip_runtime.h>
#include <stdint.h>

// Forbid mul+add contraction: pk_fma would change rounding vs the reference's
// separate mul/add ops. Critical scalar math also uses explicit __f*_rn.
#pragma clang fp contract(off)

typedef unsigned long long u64;
typedef unsigned int u32;
typedef float v2f __attribute__((ext_vector_type(2)));

#define BB 8
#define NN 4096
#define SS 1024
#define EE 102      // int(0.1 * 1024)
#define NBB 3072    // N - S
#define FT 256      // fps threads (4 waves, 1 per SIMD)
#define PT 16       // points per thread (contiguous: thread t owns [16t,16t+16))
#define SEL_T 512

// DPP wave64 max-reduce step (bound_ctrl: OOB lanes read 0; values >= 0).
template <int CTRL>
__device__ __forceinline__ float maxdpp(float v) {
  int m = __builtin_amdgcn_update_dpp(0, __float_as_int(v), CTRL, 0xf, 0xf, true);
  return fmaxf(v, __int_as_float(m));
}

// ---------------- FPS kernel: one block per batch ----------------
// Exact replica of _fps_order: d = (dx*dx+dy*dy)+dz*dz (no FMA), mind=min,
// argmax with lowest-index-first ties. r12 base (scalar register arrays +
// 64KB AoS mirror = broadcast source AND PromoteAlloca demotion shield;
// hist[] in LDS; winner lane publishes its own key; serial interleaved
// select -- r8/r13 proved flat extraction loses). ONE change vs r12:
// NO per-iteration s_barrier. Cross-wave sync is a tagged-key spin:
// key low byte = it&255; waves poll the 4 slots (volatile LDS reads)
// until all tags match. Skew is self-limited to <1 iteration (to write
// iter k+1 a wave must first read all keys of iter k), so the 2-slot
// double buffer cannot be clobbered. Tag sits below the index field ->
// key comparisons (value desc, index asc) are unchanged.
__global__ __launch_bounds__(FT) void fps_kernel(const float* __restrict__ x,
                                                 int* __restrict__ idxs) {
  const int b = blockIdx.x;
  const int t = threadIdx.x;
  const int w = t >> 6;
  const int lane = t & 63;
  const float* xb = x + (size_t)b * NN * 3;

  __shared__ float4 lxyz[NN];   // 64 KB coord mirror (+ demotion shield)
  __shared__ int hist[NN];      // 16 KB FPS order (LDS-local until flush)
  __shared__ u64 rkey[2][4];    // per-wave tagged keys, double-buffered

  float px[PT], py[PT], pz[PT], mind[PT];

  // load 16 contiguous points = 12 float4 per thread (fully coalesced block)
  const float4* xb4 = (const float4*)xb;
  float4 f[12];
#pragma unroll
  for (int j = 0; j < 12; ++j) f[j] = xb4[t * 12 + j];
#pragma unroll
  for (int g = 0; g < 4; ++g) {
    float4 a = f[g * 3 + 0], c = f[g * 3 + 1], d = f[g * 3 + 2];
    px[g * 4 + 0] = a.x; py[g * 4 + 0] = a.y; pz[g * 4 + 0] = a.z;
    px[g * 4 + 1] = a.w; py[g * 4 + 1] = c.x; pz[g * 4 + 1] = c.y;
    px[g * 4 + 2] = c.z; py[g * 4 + 2] = c.w; pz[g * 4 + 2] = d.x;
    px[g * 4 + 3] = d.y; py[g * 4 + 3] = d.z; pz[g * 4 + 3] = d.w;
  }
#pragma unroll
  for (int q = 0; q < PT; ++q) {
    lxyz[t * PT + q] = make_float4(px[q], py[q], pz[q], 0.0f);
    mind[q] = __builtin_inff();
  }
  if (t == 0) hist[0] = 0;
  // init all 8 key slots with tag 0xFF (!= tags 0/1 of the first two iters)
  if (t < 8) ((volatile u64*)&rkey[0][0])[t] = 0xFFull;
  __syncthreads();   // one-time init barrier (lxyz + slots visible)

  float4 lp = lxyz[0];
  for (int it = 0; it < NN - 1; ++it) {
    const int buf = it & 1;
    const u32 tag = (u32)(it & 0xFF);
    v2f lx2; lx2.x = lp.x; lx2.y = lp.x;
    v2f ly2; ly2.x = lp.y; ly2.y = lp.y;
    v2f lz2; lz2.x = lp.z; lz2.y = lp.z;

    // phase 1: packed-f32 distances + mind update + serial lowest-index
    // select (proven; per-half rn rounding == scalar rn)
    float bestv = -1.0f;
    int bq = 0;
#pragma unroll
    for (int q = 0; q < 8; ++q) {
      v2f X; X.x = px[2 * q]; X.y = px[2 * q + 1];
      v2f Y; Y.x = py[2 * q]; Y.y = py[2 * q + 1];
      v2f Z; Z.x = pz[2 * q]; Z.y = pz[2 * q + 1];
      v2f dx = X - lx2;
      v2f dy = Y - ly2;
      v2f dz = Z - lz2;
      v2f dd = (dx * dx + dy * dy) + dz * dz;
      float m0 = fminf(mind[2 * q], dd.x);
      float m1 = fminf(mind[2 * q + 1], dd.y);
      mind[2 * q] = m0;
      mind[2 * q + 1] = m1;
      // ascending q => ascending global index; strict '>' keeps lowest index
      if (m0 > bestv) { bestv = m0; bq = 2 * q; }
      if (m1 > bestv) { bestv = m1; bq = 2 * q + 1; }
    }

    // phase 2: wave64 max via DPP (all VALU): result in lane 63
    float r = bestv;
    r = maxdpp<0x111>(r);   // row_shr:1
    r = maxdpp<0x112>(r);   // row_shr:2
    r = maxdpp<0x114>(r);   // row_shr:4
    r = maxdpp<0x118>(r);   // row_shr:8
    r = maxdpp<0x142>(r);   // row_bcast:15
    r = maxdpp<0x143>(r);   // row_bcast:31
    int wmaxb = __builtin_amdgcn_readlane(__float_as_int(r), 63);

    // phase 3: first lane holding the max == lowest candidate index; that
    // lane publishes its tagged key (volatile store: ordered vs spin reads)
    u64 msk = __ballot(__float_as_int(bestv) == wmaxb);
    int flane = (int)__builtin_ctzll(msk);
    if (lane == flane) {
      int besti = t * PT + bq;
      u64 key = ((u64)(u32)wmaxb << 32) |
                ((u32)(4095 - besti) << 8) | tag;
      *(volatile u64*)&rkey[buf][w] = key;
    }

    // phase 4: spin until all 4 wave slots carry this iteration's tag
    // (volatile -> re-read each pass; condition is wave-uniform)
    u64 k0, k1, k2, k3;
    volatile u64* rk = (volatile u64*)&rkey[buf][0];
    do {
      k0 = rk[0]; k1 = rk[1]; k2 = rk[2]; k3 = rk[3];
    } while ((((k0 ^ tag) | (k1 ^ tag) | (k2 ^ tag) | (k3 ^ tag)) & 0xFFull) != 0ull);

    // phase 5: 4-way key tree (value desc, index asc; tag equal -> inert)
    u64 m01 = k0 > k1 ? k0 : k1;
    u64 m23 = k2 > k3 ? k2 : k3;
    u64 km = m01 > m23 ? m01 : m23;
    int last = 4095 - (int)((km >> 8) & 0xFFFu);
    if (t == 0) hist[it + 1] = last;   // LDS store: lgkm ack only
    lp = lxyz[last];                   // broadcast read (same addr all lanes)
  }

  // flush FPS order to global once (coalesced int4: 4096/256/4 = 4 per thread)
  __syncthreads();
  int* ig = idxs + (size_t)b * NN;
#pragma unroll
  for (int j = 0; j < NN / FT / 4; ++j) {
    ((int4*)ig)[j * FT + t] = ((const int4*)hist)[j * FT + t];
  }
}

// ------------- selection kernel: one block per batch -------------
__global__ __launch_bounds__(SEL_T) void select_kernel(const float* __restrict__ x,
                                                       const float* __restrict__ curv,
                                                       const int* __restrict__ idxs,
                                                       float* __restrict__ out) {
  const int b = blockIdx.x;
  const int t = threadIdx.x;
  __shared__ u64 ka[SS];     // sca keys: (~vbits, i)  -> ascending == desc by v
  __shared__ u64 kb[4096];   // scb keys: (vbits, i)   -> ascending, 1024 pads
  __shared__ float rmn[8], rmx[8];

  const float* cb = curv + (size_t)b * NN;
  const int* ib = idxs + (size_t)b * NN;

  float mn = __builtin_inff(), mx = -__builtin_inff();
  float cv[8];
#pragma unroll
  for (int q = 0; q < 8; ++q) {
    float v = cb[q * SEL_T + t];
    cv[q] = v;
    mn = fminf(mn, v);
    mx = fmaxf(mx, v);
  }
#pragma unroll
  for (int s = 1; s < 64; s <<= 1) {
    mn = fminf(mn, __shfl_xor(mn, s, 64));
    mx = fmaxf(mx, __shfl_xor(mx, s, 64));
  }
  if ((t & 63) == 0) { rmn[t >> 6] = mn; rmx[t >> 6] = mx; }
  __syncthreads();
  mn = rmn[0]; mx = rmx[0];
#pragma unroll
  for (int w = 1; w < 8; ++w) { mn = fminf(mn, rmn[w]); mx = fmaxf(mx, rmx[w]); }
  float denom = __fsub_rn(mx, mn);

#pragma unroll
  for (int q = 0; q < 8; ++q) {
    int i = q * SEL_T + t;
    float cn = __fdiv_rn(__fsub_rn(cv[q], mn), denom);
    int id = ib[i];
    // jnp.linspace(1,0,4096)[id] = 1 - id/4095 (true division; id=4095 -> 0)
    float sv = __fsub_rn(1.0f, __fdiv_rn((float)id, 4095.0f));
    float scv = __fmul_rn(sv, cn);   // sc >= 0 -> bits are order-monotone
    u32 vb = __float_as_uint(scv);
    if (i < SS)
      ka[i] = ((u64)(vb ^ 0xFFFFFFFFu) << 32) | (u32)i;
    else
      kb[i - SS] = ((u64)vb << 32) | (u32)(i - SS);
  }
  for (int i = NBB + t; i < 4096; i += SEL_T) kb[i] = ~0ULL;  // pads to the top
  __syncthreads();

  // bitonic sort ka ascending (n=1024, 512 pairs: one per thread)
  for (u32 k = 2; k <= SS; k <<= 1) {
    for (u32 j = k >> 1; j > 0; j >>= 1) {
      u32 p = (u32)t;
      u32 i = ((p & ~(j - 1)) << 1) | (p & (j - 1));
      u32 l = i | j;
      bool up = ((i & k) == 0);
      u64 a = ka[i], c = ka[l];
      if ((a > c) == up) { ka[i] = c; ka[l] = a; }
      __syncthreads();
    }
  }
  // bitonic sort kb ascending (n=4096, 2048 pairs: 4 per thread)
  for (u32 k = 2; k <= 4096; k <<= 1) {
    for (u32 j = k >> 1; j > 0; j >>= 1) {
#pragma unroll
      for (u32 p = (u32)t; p < 2048; p += SEL_T) {
        u32 i = ((p & ~(j - 1)) << 1) | (p & (j - 1));
        u32 l = i | j;
        bool up = ((i & k) == 0);
        u64 a = kb[i], c = kb[l];
        if ((a > c) == up) { kb[i] = c; kb[l] = a; }
      }
      __syncthreads();
    }
  }

  // final[j]: j<922 -> ba_idx[j]; else tb beats ba ? tb_idx[j] : ba_idx[j]
#pragma unroll
  for (int j0 = 0; j0 < SS; j0 += SEL_T) {
    int j = j0 + t;
    u64 A = ka[j];
    int baid = (int)(u32)(A & 0xFFFFFFFFu);
    u32 babits = ((u32)(A >> 32)) ^ 0xFFFFFFFFu;
    int fin = baid;
    if (j >= SS - EE) {
      u64 Bk = kb[2048 + j];           // largest-1024 of scb, ascending
      u32 tbbits = (u32)(Bk >> 32);
      if (tbbits > babits) fin = (int)(u32)(Bk & 0xFFFFFFFFu) + SS;
    }
    int pt = ib[fin];
    out[(size_t)b * SS + j] = (float)fin;
    const float* xp = x + ((size_t)b * NN + (size_t)pt) * 3;
    float* op = out + (size_t)BB * SS + ((size_t)b * SS + (size_t)j) * 3;
    op[0] = xp[0];
    op[1] = xp[1];
    op[2] = xp[2];
  }
}

extern "C" void kernel_launch(void* const* d_in, const int* in_sizes, int n_in,
                              void* d_out, int out_size, void* d_ws, size_t ws_size,
                              hipStream_t stream) {
  (void)in_sizes; (void)n_in; (void)out_size; (void)ws_size;
  const float* x = (const float*)d_in[0];
  const float* curv = (const float*)d_in[1];
  int* idxs = (int*)d_ws;             // B*N int32 = 128 KB scratch
  float* out = (float*)d_out;

  fps_kernel<<<BB, FT, 0, stream>>>(x, idxs);
  select_kernel<<<BB, SEL_T, 0, stream>>>(x, curv, idxs, out);
}